// Round 14
// baseline (163.396 us; speedup 1.0000x reference)
//
#include <hip/hip_runtime.h>
#include <cstddef>

#define B_   16
#define N_   4096
#define S_   1024
#define D1_  64
#define D2_  256
#define CIN_ 320
#define H_   256
#define CH_  8
#define SC_  (S_ / CH_)          // 128 source points per chunk
#define P_   (B_ * (N_ / 128))   // 512 BN partials per channel

using short8 = __attribute__((ext_vector_type(8))) short;
using f32x4  = __attribute__((ext_vector_type(4))) float;

typedef const __attribute__((address_space(1))) unsigned g1u32;
typedef __attribute__((address_space(3))) unsigned l3u32;

__device__ __forceinline__ void gl_lds16(const void* g, void* l) {
  __builtin_amdgcn_global_load_lds((g1u32*)g, (l3u32*)l, 16, 0, 0);
}

__device__ __forceinline__ float relu_f(float v) { return fmaxf(v, 0.0f); }

__device__ __forceinline__ ushort f2bf(float f) {
  unsigned u = __builtin_bit_cast(unsigned, f);
  u += 0x7fffu + ((u >> 16) & 1u);   // round-to-nearest-even
  return (ushort)(u >> 16);
}
// packed RNE f32x2 -> bf16x2 (lo = a, hi = b)
__device__ __forceinline__ unsigned f2bf2(float a, float b) {
  unsigned r;
  asm("v_cvt_pk_bf16_f32 %0, %1, %2" : "=v"(r) : "v"(a), "v"(b));
  return r;
}
__device__ __forceinline__ float bf2f(ushort u) {
  return __builtin_bit_cast(float, (unsigned)u << 16);
}

// ---------------------------------------------------------------------------
// prep_knn (merged preprocessing, independent work ranges):
//   [0,4096)      points2 [B][256][S] -> p2tb [B][S][256] bf16 (32x32 tiles)
//   [4096,4136)   W1 fp32 -> bf16
//   [4136,4168)   W2 fp32 -> bf16
//   [4168,6216)   chunked 3-NN partials (b = g&15 pins XCD)
// ---------------------------------------------------------------------------
__global__ __launch_bounds__(256) void prep_knn(
    const float* __restrict__ points2, const float* __restrict__ W1,
    const float* __restrict__ W2, const float* __restrict__ xyz1,
    const float* __restrict__ xyz2, ushort* __restrict__ p2tb,
    ushort* __restrict__ W1b, ushort* __restrict__ W2b,
    float* __restrict__ pd, int* __restrict__ pi) {
  __shared__ union { float tile[32][33]; float4 P[SC_]; } sm;
  int g = blockIdx.x, t = threadIdx.x;
  if (g < 4096) {
    int z = g >> 8, rem = g & 255;
    int c0 = (rem & 31) * 32;        // S dim
    int r0 = (rem >> 5) * 32;        // D2 dim
    const float* in = points2 + (size_t)z * D2_ * S_;
    ushort* out = p2tb + (size_t)z * S_ * D2_;
    int tx = t & 31, ty = t >> 5;
#pragma unroll
    for (int j = 0; j < 4; ++j) {
      int r = r0 + ty + j * 8;
      sm.tile[ty + j * 8][tx] = in[(size_t)r * S_ + c0 + tx];
    }
    __syncthreads();
#pragma unroll
    for (int j = 0; j < 4; ++j) {
      int c = c0 + ty + j * 8;
      out[(size_t)c * D2_ + r0 + tx] = f2bf(sm.tile[tx][ty + j * 8]);
    }
  } else if (g < 4168) {
    int g2 = g - 4096;
    const float* src = (g2 < 40) ? W1 : W2;
    ushort* dst = (g2 < 40) ? W1b : W2b;
    int base = ((g2 < 40) ? g2 : g2 - 40) * 2048 + t * 8;
    float4 a = *(const float4*)&src[base];
    float4 b = *(const float4*)&src[base + 4];
    short8 r;
    ((unsigned*)&r)[0] = f2bf2(a.x, a.y);
    ((unsigned*)&r)[1] = f2bf2(a.z, a.w);
    ((unsigned*)&r)[2] = f2bf2(b.x, b.y);
    ((unsigned*)&r)[3] = f2bf2(b.z, b.w);
    *(short8*)&dst[base] = r;
  } else {
    int gk = g - 4168;                       // 0..2047
    int b = gk & 15;                         // XCD pin
    int ch = (gk >> 4) & 7;
    int n = (gk >> 7) * 256 + t;
    const float* x2b = xyz2 + (size_t)b * 3 * S_ + ch * SC_;
    if (t < SC_) {
      float x = x2b[t], y = x2b[S_ + t], z = x2b[2 * S_ + t];
      sm.P[t] = make_float4(-2.f * x, -2.f * y, -2.f * z, x * x + y * y + z * z);
    }
    __syncthreads();

    const float* x1b = xyz1 + (size_t)b * 3 * N_;
    float px = x1b[n], py = x1b[N_ + n], pz = x1b[2 * N_ + n];
    float sq1 = px * px + py * py + pz * pz;

    float d0 = 1e30f, d1 = 1e30f, d2 = 1e30f;
    int i0 = 0, i1 = 0, i2 = 0;
#pragma unroll 4
    for (int s2 = 0; s2 < SC_; ++s2) {
      float4 p = sm.P[s2];
      float d = fmaf(px, p.x, fmaf(py, p.y, fmaf(pz, p.z, p.w)));
      int gi = ch * SC_ + s2;
      if (d < d2) {
        if (d < d1) {
          if (d < d0) { d2 = d1; i2 = i1; d1 = d0; i1 = i0; d0 = d; i0 = gi; }
          else        { d2 = d1; i2 = i1; d1 = d;  i1 = gi; }
        } else        { d2 = d;  i2 = gi; }
      }
    }
    size_t base = (((size_t)b * N_ + n) * CH_ + ch) * 3;
    pd[base] = d0 + sq1; pd[base + 1] = d1 + sq1; pd[base + 2] = d2 + sq1;
    pi[base] = i0; pi[base + 1] = i1; pi[base + 2] = i2;
  }
}

// ---------------------------------------------------------------------------
// build_fused: per block = 16 points of one batch (b = g&15 pins XCD).
// ---------------------------------------------------------------------------
__global__ __launch_bounds__(256) void build_fused(
    const float* __restrict__ points1,   // [B][64][N] fp32
    const ushort* __restrict__ p2tb,     // [B][S][256] bf16
    const float* __restrict__ pd, const int* __restrict__ pi,
    ushort* __restrict__ xt) {
  __shared__ int   lidx[16][3];
  __shared__ float lw[16][3];
  __shared__ ushort p1t[16][72];
  int g = blockIdx.x, t = threadIdx.x;
  int b = g & 15;
  int p0 = (g >> 4) * 16;

  if (t < 16) {
    size_t pb = (size_t)b * N_ + p0 + t;
    const float* pdp = pd + pb * 24;
    const int*   pip = pi + pb * 24;
    float d0 = 1e30f, d1 = 1e30f, d2 = 1e30f;
    int i0 = 0, i1 = 0, i2 = 0;
#pragma unroll
    for (int k = 0; k < 24; ++k) {
      float d = pdp[k];
      int gi = pip[k];
      if (d < d2) {
        if (d < d1) {
          if (d < d0) { d2 = d1; i2 = i1; d1 = d0; i1 = i0; d0 = d; i0 = gi; }
          else        { d2 = d1; i2 = i1; d1 = d;  i1 = gi; }
        } else        { d2 = d;  i2 = gi; }
      }
    }
    float r0 = 1.0f / (d0 + 1e-8f);
    float r1 = 1.0f / (d1 + 1e-8f);
    float r2 = 1.0f / (d2 + 1e-8f);
    float rs = 1.0f / (r0 + r1 + r2);
    lidx[t][0] = i0; lidx[t][1] = i1; lidx[t][2] = i2;
    lw[t][0] = r0 * rs; lw[t][1] = r1 * rs; lw[t][2] = r2 * rs;
  }

  {
    int c = t >> 2, q4 = t & 3;
    float4 v = *(const float4*)&points1[((size_t)b * D1_ + c) * N_ + p0 + q4 * 4];
    p1t[q4 * 4 + 0][c] = f2bf(v.x);
    p1t[q4 * 4 + 1][c] = f2bf(v.y);
    p1t[q4 * 4 + 2][c] = f2bf(v.z);
    p1t[q4 * 4 + 3][c] = f2bf(v.w);
  }
  __syncthreads();

  int pl = t >> 4, q = t & 15;
  size_t pb = (size_t)b * N_ + p0 + pl;
  int i0 = lidx[pl][0], i1 = lidx[pl][1], i2 = lidx[pl][2];
  float w0 = lw[pl][0], w1 = lw[pl][1], w2 = lw[pl][2];
  const ushort* R0 = p2tb + ((size_t)b * S_ + i0) * D2_;
  const ushort* R1 = p2tb + ((size_t)b * S_ + i1) * D2_;
  const ushort* R2 = p2tb + ((size_t)b * S_ + i2) * D2_;
  ushort* o = xt + pb * CIN_;

  if (q < 8)
    *(short8*)(o + q * 8) = *(const short8*)&p1t[pl][q * 8];

#pragma unroll
  for (int it = 0; it < 2; ++it) {
    int c = it * 16 + q;               // 16B-chunk index 0..31
    short8 a = *(const short8*)&R0[c * 8];
    short8 d = *(const short8*)&R1[c * 8];
    short8 e = *(const short8*)&R2[c * 8];
    short8 r;
#pragma unroll
    for (int u = 0; u < 4; ++u) {
      float v0 = w0 * bf2f((ushort)a[2 * u]) + w1 * bf2f((ushort)d[2 * u]) +
                 w2 * bf2f((ushort)e[2 * u]);
      float v1 = w0 * bf2f((ushort)a[2 * u + 1]) + w1 * bf2f((ushort)d[2 * u + 1]) +
                 w2 * bf2f((ushort)e[2 * u + 1]);
      ((unsigned*)&r)[u] = f2bf2(v0, v1);
    }
    *(short8*)(o + D1_ + c * 8) = r;
  }
}

// ---------------------------------------------------------------------------
// MFMA GEMM, 2-phase pipeline, 3 blocks/CU (50 KB LDS):
//   A: global_load_lds double-buffer (swizzled source, both-sides rule #21).
//   B: SINGLE buffer, reg-staged — chunk t+1 loaded to regs early (latency
//      hidden under compute), transformed (BNIN: relu(x*sc+sh)) and
//      ds_written after the barrier.
//   Epilogue: C-tile and S1/S2 stats TIME-multiplexed in one LDS region
//      (sequential phases, barrier-separated) instead of co-resident.
// ---------------------------------------------------------------------------
template <int K, bool BNIN>
__global__ __launch_bounds__(256) void gemm_pipe(
    const ushort* __restrict__ Wb, const ushort* __restrict__ Xt,
    const float* __restrict__ bias, const float* __restrict__ scin,
    const float* __restrict__ shin, ushort* __restrict__ Yt,
    float* __restrict__ ps1, float* __restrict__ ps2) {
  constexpr int NT = K / 64;
  __shared__ union SM {
    struct { ushort A[2][128][64]; ushort B1[128][64]; } st;   // 48 KiB
    struct { ushort C[128][132]; } e1;                         // 33 KiB
    struct { float S1[128][33]; float S2[128][33]; } e2;       // 33 KiB
  } sm;
  __shared__ float scs_l[H_], shs_l[H_];

  int b  = blockIdx.z;
  int n0 = blockIdx.x * 128;
  int m0 = blockIdx.y * 128;
  int tid = threadIdx.x;
  int lane = tid & 63, wid = tid >> 6;
  int wm = (wid >> 1) * 64, wn = (wid & 1) * 64;
  int lr = lane & 15, hi = lane >> 4;
  size_t bn0 = (size_t)b * N_ + n0;

  if (BNIN) {
    for (int i = tid; i < K; i += 256) { scs_l[i] = scin[i]; shs_l[i] = shin[i]; }
  }

  const char* Agb = (const char*)(Wb + (size_t)m0 * K);
  const ushort* Bg = Xt + bn0 * K;
  const size_t rowB = (size_t)K * 2;

  // per-lane chunk mapping (both-sides swizzle): chunk m -> row=m>>3,
  // physical slot s=m&7, logical 16B-col c=((m&7)-row)&7.
  size_t gsrc[4];
  int    ldst[4];
  int    brow[4], bcol[4];
#pragma unroll
  for (int r = 0; r < 4; ++r) {
    int m = (wid * 4 + r) * 64 + lane;
    int row = m >> 3;
    int c = ((m & 7) - row) & 7;
    gsrc[r] = (size_t)row * rowB + (size_t)c * 16;
    ldst[r] = m * 16;
    brow[r] = row; bcol[r] = c;
  }

  auto stageA = [&](int buf, int kc) {
    char* bA = (char*)sm.st.A[buf];
    size_t kb = (size_t)kc * 128;
#pragma unroll
    for (int r = 0; r < 4; ++r)
      gl_lds16(Agb + gsrc[r] + kb, bA + ldst[r]);
  };

  short8 braw[4];
  auto loadB = [&](int kc) {
#pragma unroll
    for (int r = 0; r < 4; ++r)
      braw[r] = *(const short8*)&Bg[(size_t)brow[r] * K + kc * 64 + bcol[r] * 8];
  };
  auto writeB = [&](int kc) {
#pragma unroll
    for (int r = 0; r < 4; ++r) {
      short8 pk = braw[r];
      if (BNIN) {
        int kb = kc * 64 + bcol[r] * 8;
#pragma unroll
        for (int u = 0; u < 4; ++u) {
          float y0 = relu_f(bf2f((ushort)braw[r][2 * u]) * scs_l[kb + 2 * u] +
                            shs_l[kb + 2 * u]);
          float y1 = relu_f(bf2f((ushort)braw[r][2 * u + 1]) * scs_l[kb + 2 * u + 1] +
                            shs_l[kb + 2 * u + 1]);
          ((unsigned*)&pk)[u] = f2bf2(y0, y1);
        }
      }
      *(short8*)((char*)sm.st.B1 + ldst[r]) = pk;
    }
  };

  f32x4 acc[4][4] = {};

  // prologue: A chunk0 DMA + B chunk0 regs, then publish B
  stageA(0, 0);
  loadB(0);
  __syncthreads();            // drains A-DMA + braw loads (+ scs fill)
  writeB(0);
  __syncthreads();            // B chunk0 visible

  int cur = 0;
  for (int t = 0; t < NT; ++t) {
    if (t + 1 < NT) {
      stageA(cur ^ 1, t + 1);   // DMA into other A buf
      loadB(t + 1);             // B into regs; latency hides under compute
    }
#pragma unroll
    for (int ks = 0; ks < 2; ++ks) {
      short8 af[4], bv[4];
#pragma unroll
      for (int i = 0; i < 4; ++i) {
        int rA = wm + i * 16 + lr;
        int rB = wn + i * 16 + lr;
        int sA = (rA + ks * 4 + hi) & 7;
        int sB = (rB + ks * 4 + hi) & 7;
        af[i] = *(const short8*)&sm.st.A[cur][rA][sA * 8];
        bv[i] = *(const short8*)&sm.st.B1[rB][sB * 8];
      }
#pragma unroll
      for (int mf = 0; mf < 4; ++mf)
#pragma unroll
        for (int nf = 0; nf < 4; ++nf)
          acc[mf][nf] = __builtin_amdgcn_mfma_f32_16x16x32_bf16(
              af[mf], bv[nf], acc[mf][nf], 0, 0, 0);
    }
    __syncthreads();            // B reads done; A(t+1) DMA drained
    if (t + 1 < NT) {
      writeB(t + 1);
      __syncthreads();          // B(t+1) visible
    }
    cur ^= 1;
  }

  // ---- epilogue phase 1: bias + stats in regs, C via LDS, coalesced store
  float sum1[4][4] = {}, sum2[4][4] = {};
#pragma unroll
  for (int mf = 0; mf < 4; ++mf) {
#pragma unroll
    for (int nf = 0; nf < 4; ++nf) {
      int n = wn + nf * 16 + lr;
      float v[4];
#pragma unroll
      for (int j = 0; j < 4; ++j) {
        v[j] = acc[mf][nf][j] + bias[m0 + wm + mf * 16 + hi * 4 + j];
        sum1[mf][j] += v[j];
        sum2[mf][j] += v[j] * v[j];
      }
      ushort4 u;
      ((unsigned*)&u)[0] = f2bf2(v[0], v[1]);
      ((unsigned*)&u)[1] = f2bf2(v[2], v[3]);
      *(ushort4*)&sm.e1.C[n][wm + mf * 16 + hi * 4] = u;
    }
  }
  __syncthreads();
  {
    int rown = tid >> 4, q = tid & 15;
#pragma unroll
    for (int p = 0; p < 8; ++p) {
      int n = p * 16 + rown;
      short8 val = *(const short8*)&sm.e1.C[n][q * 8];
      *(short8*)&Yt[(bn0 + n) * H_ + m0 + q * 8] = val;
    }
  }
  __syncthreads();            // C reads done before S1/S2 overwrite (same LDS)

  // ---- epilogue phase 2: BN partial stats reduce ----
  int col = (wid & 1) * 16 + lr;
#pragma unroll
  for (int mf = 0; mf < 4; ++mf)
#pragma unroll
    for (int j = 0; j < 4; ++j) {
      int c = wm + mf * 16 + hi * 4 + j;
      sm.e2.S1[c][col] = sum1[mf][j];
      sm.e2.S2[c][col] = sum2[mf][j];
    }
  __syncthreads();
  int pidx = b * gridDim.x + blockIdx.x;
  int c = tid & 127;
  float s = 0.f;
  if (tid < 128) {
#pragma unroll
    for (int k = 0; k < 32; ++k) s += sm.e2.S1[c][k];
    ps1[(size_t)pidx * H_ + m0 + c] = s;
  } else {
#pragma unroll
    for (int k = 0; k < 32; ++k) s += sm.e2.S2[c][k];
    ps2[(size_t)pidx * H_ + m0 + c] = s;
  }
}

// ---------------------------------------------------------------------------
// Reduce P_ partials per channel -> BN scale/shift. One block per channel.
// ---------------------------------------------------------------------------
__global__ __launch_bounds__(256) void bn_stats_fin(
    const float* __restrict__ ps1, const float* __restrict__ ps2,
    const float* __restrict__ gamma, const float* __restrict__ beta,
    float* __restrict__ sc, float* __restrict__ sh) {
  int c = blockIdx.x, t = threadIdx.x;
  float s1 = ps1[(size_t)t * H_ + c] + ps1[(size_t)(t + 256) * H_ + c];
  float s2 = ps2[(size_t)t * H_ + c] + ps2[(size_t)(t + 256) * H_ + c];
  __shared__ float S1[256], S2[256];
  S1[t] = s1; S2[t] = s2;
  __syncthreads();
  for (int off = 128; off > 0; off >>= 1) {
    if (t < off) { S1[t] += S1[t + off]; S2[t] += S2[t + off]; }
    __syncthreads();
  }
  if (t == 0) {
    const float inv = 1.0f / (float)(B_ * N_);
    float mean = S1[0] * inv;
    float var  = S2[0] * inv - mean * mean;
    float g    = gamma[c] * rsqrtf(var + 1e-5f);
    sc[c] = g;
    sh[c] = beta[c] - mean * g;
  }
}

// ---------------------------------------------------------------------------
// Final: h2b[b][n][m] bf16 (pre-BN) -> BN+ReLU -> d_out[b][m][n] fp32.
// ---------------------------------------------------------------------------
__global__ __launch_bounds__(256) void bn_out_t(
    const ushort* __restrict__ Hb, const float* __restrict__ sc,
    const float* __restrict__ sh, float* __restrict__ out) {
  __shared__ float tile[32][132];   // [n][m]
  int b = blockIdx.z;
  int n0 = blockIdx.x * 32, m0 = blockIdx.y * 128;
  int t = threadIdx.x;
  int m8 = (t & 15) * 8;
  f32x4 sa = *(const f32x4*)&sc[m0 + m8];
  f32x4 sb = *(const f32x4*)&sc[m0 + m8 + 4];
  f32x4 ha = *(const f32x4*)&sh[m0 + m8];
  f32x4 hb = *(const f32x4*)&sh[m0 + m8 + 4];
  size_t bn0 = (size_t)b * N_ + n0;
#pragma unroll
  for (int pass = 0; pass < 2; ++pass) {
    int n = pass * 16 + (t >> 4);
    short8 v = *(const short8*)&Hb[(bn0 + n) * H_ + m0 + m8];
#pragma unroll
    for (int e = 0; e < 4; ++e) {
      tile[n][m8 + e]     = relu_f(bf2f((ushort)v[e]) * sa[e] + ha[e]);
      tile[n][m8 + 4 + e] = relu_f(bf2f((ushort)v[e + 4]) * sb[e] + hb[e]);
    }
  }
  __syncthreads();
  int m = t >> 1, nh = (t & 1) * 16;
  float* orow = out + ((size_t)b * H_ + m0 + m) * N_ + n0 + nh;
#pragma unroll
  for (int j = 0; j < 4; ++j) {
    float4 v;
    v.x = tile[nh + j * 4 + 0][m];
    v.y = tile[nh + j * 4 + 1][m];
    v.z = tile[nh + j * 4 + 2][m];
    v.w = tile[nh + j * 4 + 3][m];
    *(float4*)&orow[j * 4] = v;
  }
}

// ---------------------------------------------------------------------------
extern "C" void kernel_launch(void* const* d_in, const int* in_sizes, int n_in,
                              void* d_out, int out_size, void* d_ws,
                              size_t ws_size, hipStream_t stream) {
  const float* xyz1    = (const float*)d_in[0];
  const float* xyz2    = (const float*)d_in[1];
  const float* points1 = (const float*)d_in[2];
  const float* points2 = (const float*)d_in[3];
  const float* W1  = (const float*)d_in[4];
  const float* b1  = (const float*)d_in[5];
  const float* g1  = (const float*)d_in[6];
  const float* bt1 = (const float*)d_in[7];
  const float* W2  = (const float*)d_in[8];
  const float* b2  = (const float*)d_in[9];
  const float* g2  = (const float*)d_in[10];
  const float* bt2 = (const float*)d_in[11];
  float* out = (float*)d_out;
  char* cur = (char*)d_ws;
  auto alloc = [&](size_t bytes) { char* p = cur; cur += (bytes + 255) & ~255ull; return p; };

  ushort* p2tb = (ushort*)alloc((size_t)B_ * S_ * D2_ * 2);   // [B][S][256]
  float*  pd   = (float*)alloc((size_t)B_ * N_ * CH_ * 3 * 4);
  int*    pi   = (int*)alloc((size_t)B_ * N_ * CH_ * 3 * 4);
  ushort* W1b  = (ushort*)alloc((size_t)H_ * CIN_ * 2);
  ushort* W2b  = (ushort*)alloc((size_t)H_ * H_ * 2);
  ushort* xct  = (ushort*)alloc((size_t)B_ * N_ * CIN_ * 2);  // [B][N][320]
  ushort* h1t  = (ushort*)alloc((size_t)B_ * N_ * H_ * 2);    // [B][N][256]
  float*  ps1  = (float*)alloc((size_t)P_ * H_ * 4);
  float*  ps2  = (float*)alloc((size_t)P_ * H_ * 4);
  float*  sc1  = (float*)alloc(H_ * 4);
  float*  sh1  = (float*)alloc(H_ * 4);
  float*  sc2  = (float*)alloc(H_ * 4);
  float*  sh2  = (float*)alloc(H_ * 4);
  ushort* h2b  = xct;   // overlay: xct dead after gemm1

  // 1) points2 transpose + weight conversions + chunked 3-NN (merged)
  prep_knn<<<4096 + 40 + 32 + 2048, 256, 0, stream>>>(
      points2, W1, W2, xyz1, xyz2, p2tb, W1b, W2b, pd, pi);

  // 2) merge + points1-transpose + interp -> xct [B][N][320] bf16
  build_fused<<<B_ * N_ / 16, 256, 0, stream>>>(points1, p2tb, pd, pi, xct);

  // 3) layer-1 GEMM + fused stats
  gemm_pipe<CIN_, false><<<dim3(N_ / 128, H_ / 128, B_), 256, 0, stream>>>(
      W1b, xct, b1, nullptr, nullptr, h1t, ps1, ps2);
  // 4) BN1 fold
  bn_stats_fin<<<H_, 256, 0, stream>>>(ps1, ps2, g1, bt1, sc1, sh1);

  // 5) layer-2 GEMM (BN1+ReLU at B-staging) + fused stats
  gemm_pipe<H_, true><<<dim3(N_ / 128, H_ / 128, B_), 256, 0, stream>>>(
      W2b, h1t, b2, sc1, sh1, h2b, ps1, ps2);
  // 6) BN2 fold
  bn_stats_fin<<<H_, 256, 0, stream>>>(ps1, ps2, g2, bt2, sc2, sh2);

  // 7) final BN+ReLU + transpose to d_out [b][m][n] fp32
  bn_out_t<<<dim3(N_ / 32, H_ / 128, B_), 256, 0, stream>>>(h2b, sc2, sh2, out);
}

// Round 16
// 154.357 us; speedup vs baseline: 1.0586x; 1.0586x over previous
//
#include <hip/hip_runtime.h>
#include <cstddef>

#define B_   16
#define N_   4096
#define S_   1024
#define D1_  64
#define D2_  256
#define CIN_ 320
#define H_   256
#define CH_  8
#define SC_  (S_ / CH_)          // 128 source points per chunk
#define P_   (B_ * (N_ / 128))   // 512 BN partials per channel

using short8 = __attribute__((ext_vector_type(8))) short;
using f32x4  = __attribute__((ext_vector_type(4))) float;

typedef const __attribute__((address_space(1))) unsigned g1u32;
typedef __attribute__((address_space(3))) unsigned l3u32;

__device__ __forceinline__ void gl_lds16(const void* g, void* l) {
  __builtin_amdgcn_global_load_lds((g1u32*)g, (l3u32*)l, 16, 0, 0);
}

__device__ __forceinline__ float relu_f(float v) { return fmaxf(v, 0.0f); }

__device__ __forceinline__ ushort f2bf(float f) {
  unsigned u = __builtin_bit_cast(unsigned, f);
  u += 0x7fffu + ((u >> 16) & 1u);   // round-to-nearest-even
  return (ushort)(u >> 16);
}
// packed RNE f32x2 -> bf16x2 (lo = a, hi = b)
__device__ __forceinline__ unsigned f2bf2(float a, float b) {
  unsigned r;
  asm("v_cvt_pk_bf16_f32 %0, %1, %2" : "=v"(r) : "v"(a), "v"(b));
  return r;
}
__device__ __forceinline__ float bf2f(ushort u) {
  return __builtin_bit_cast(float, (unsigned)u << 16);
}

// ---------------------------------------------------------------------------
// prep_knn (merged preprocessing, independent work ranges):
//   [0,4096)      points2 [B][256][S] -> p2tb [B][S][256] bf16 (32x32 tiles)
//   [4096,4136)   W1 fp32 -> bf16
//   [4136,4168)   W2 fp32 -> bf16
//   [4168,6216)   chunked 3-NN partials (b = g&15 pins XCD)
// ---------------------------------------------------------------------------
__global__ __launch_bounds__(256) void prep_knn(
    const float* __restrict__ points2, const float* __restrict__ W1,
    const float* __restrict__ W2, const float* __restrict__ xyz1,
    const float* __restrict__ xyz2, ushort* __restrict__ p2tb,
    ushort* __restrict__ W1b, ushort* __restrict__ W2b,
    float* __restrict__ pd, int* __restrict__ pi) {
  __shared__ union { float tile[32][33]; float4 P[SC_]; } sm;
  int g = blockIdx.x, t = threadIdx.x;
  if (g < 4096) {
    int z = g >> 8, rem = g & 255;
    int c0 = (rem & 31) * 32;        // S dim
    int r0 = (rem >> 5) * 32;        // D2 dim
    const float* in = points2 + (size_t)z * D2_ * S_;
    ushort* out = p2tb + (size_t)z * S_ * D2_;
    int tx = t & 31, ty = t >> 5;
#pragma unroll
    for (int j = 0; j < 4; ++j) {
      int r = r0 + ty + j * 8;
      sm.tile[ty + j * 8][tx] = in[(size_t)r * S_ + c0 + tx];
    }
    __syncthreads();
#pragma unroll
    for (int j = 0; j < 4; ++j) {
      int c = c0 + ty + j * 8;
      out[(size_t)c * D2_ + r0 + tx] = f2bf(sm.tile[tx][ty + j * 8]);
    }
  } else if (g < 4168) {
    int g2 = g - 4096;
    const float* src = (g2 < 40) ? W1 : W2;
    ushort* dst = (g2 < 40) ? W1b : W2b;
    int base = ((g2 < 40) ? g2 : g2 - 40) * 2048 + t * 8;
    float4 a = *(const float4*)&src[base];
    float4 b = *(const float4*)&src[base + 4];
    short8 r;
    ((unsigned*)&r)[0] = f2bf2(a.x, a.y);
    ((unsigned*)&r)[1] = f2bf2(a.z, a.w);
    ((unsigned*)&r)[2] = f2bf2(b.x, b.y);
    ((unsigned*)&r)[3] = f2bf2(b.z, b.w);
    *(short8*)&dst[base] = r;
  } else {
    int gk = g - 4168;                       // 0..2047
    int b = gk & 15;                         // XCD pin
    int ch = (gk >> 4) & 7;
    int n = (gk >> 7) * 256 + t;
    const float* x2b = xyz2 + (size_t)b * 3 * S_ + ch * SC_;
    if (t < SC_) {
      float x = x2b[t], y = x2b[S_ + t], z = x2b[2 * S_ + t];
      sm.P[t] = make_float4(-2.f * x, -2.f * y, -2.f * z, x * x + y * y + z * z);
    }
    __syncthreads();

    const float* x1b = xyz1 + (size_t)b * 3 * N_;
    float px = x1b[n], py = x1b[N_ + n], pz = x1b[2 * N_ + n];
    float sq1 = px * px + py * py + pz * pz;

    float d0 = 1e30f, d1 = 1e30f, d2 = 1e30f;
    int i0 = 0, i1 = 0, i2 = 0;
#pragma unroll 4
    for (int s2 = 0; s2 < SC_; ++s2) {
      float4 p = sm.P[s2];
      float d = fmaf(px, p.x, fmaf(py, p.y, fmaf(pz, p.z, p.w)));
      int gi = ch * SC_ + s2;
      if (d < d2) {
        if (d < d1) {
          if (d < d0) { d2 = d1; i2 = i1; d1 = d0; i1 = i0; d0 = d; i0 = gi; }
          else        { d2 = d1; i2 = i1; d1 = d;  i1 = gi; }
        } else        { d2 = d;  i2 = gi; }
      }
    }
    size_t base = (((size_t)b * N_ + n) * CH_ + ch) * 3;
    pd[base] = d0 + sq1; pd[base + 1] = d1 + sq1; pd[base + 2] = d2 + sq1;
    pi[base] = i0; pi[base + 1] = i1; pi[base + 2] = i2;
  }
}

// ---------------------------------------------------------------------------
// build_fused: per block = 16 points of one batch (b = g&15 pins XCD).
// ---------------------------------------------------------------------------
__global__ __launch_bounds__(256) void build_fused(
    const float* __restrict__ points1,   // [B][64][N] fp32
    const ushort* __restrict__ p2tb,     // [B][S][256] bf16
    const float* __restrict__ pd, const int* __restrict__ pi,
    ushort* __restrict__ xt) {
  __shared__ int   lidx[16][3];
  __shared__ float lw[16][3];
  __shared__ ushort p1t[16][72];
  int g = blockIdx.x, t = threadIdx.x;
  int b = g & 15;
  int p0 = (g >> 4) * 16;

  if (t < 16) {
    size_t pb = (size_t)b * N_ + p0 + t;
    const float* pdp = pd + pb * 24;
    const int*   pip = pi + pb * 24;
    float d0 = 1e30f, d1 = 1e30f, d2 = 1e30f;
    int i0 = 0, i1 = 0, i2 = 0;
#pragma unroll
    for (int k = 0; k < 24; ++k) {
      float d = pdp[k];
      int gi = pip[k];
      if (d < d2) {
        if (d < d1) {
          if (d < d0) { d2 = d1; i2 = i1; d1 = d0; i1 = i0; d0 = d; i0 = gi; }
          else        { d2 = d1; i2 = i1; d1 = d;  i1 = gi; }
        } else        { d2 = d;  i2 = gi; }
      }
    }
    float r0 = 1.0f / (d0 + 1e-8f);
    float r1 = 1.0f / (d1 + 1e-8f);
    float r2 = 1.0f / (d2 + 1e-8f);
    float rs = 1.0f / (r0 + r1 + r2);
    lidx[t][0] = i0; lidx[t][1] = i1; lidx[t][2] = i2;
    lw[t][0] = r0 * rs; lw[t][1] = r1 * rs; lw[t][2] = r2 * rs;
  }

  {
    int c = t >> 2, q4 = t & 3;
    float4 v = *(const float4*)&points1[((size_t)b * D1_ + c) * N_ + p0 + q4 * 4];
    p1t[q4 * 4 + 0][c] = f2bf(v.x);
    p1t[q4 * 4 + 1][c] = f2bf(v.y);
    p1t[q4 * 4 + 2][c] = f2bf(v.z);
    p1t[q4 * 4 + 3][c] = f2bf(v.w);
  }
  __syncthreads();

  int pl = t >> 4, q = t & 15;
  size_t pb = (size_t)b * N_ + p0 + pl;
  int i0 = lidx[pl][0], i1 = lidx[pl][1], i2 = lidx[pl][2];
  float w0 = lw[pl][0], w1 = lw[pl][1], w2 = lw[pl][2];
  const ushort* R0 = p2tb + ((size_t)b * S_ + i0) * D2_;
  const ushort* R1 = p2tb + ((size_t)b * S_ + i1) * D2_;
  const ushort* R2 = p2tb + ((size_t)b * S_ + i2) * D2_;
  ushort* o = xt + pb * CIN_;

  if (q < 8)
    *(short8*)(o + q * 8) = *(const short8*)&p1t[pl][q * 8];

#pragma unroll
  for (int it = 0; it < 2; ++it) {
    int c = it * 16 + q;               // 16B-chunk index 0..31
    short8 a = *(const short8*)&R0[c * 8];
    short8 d = *(const short8*)&R1[c * 8];
    short8 e = *(const short8*)&R2[c * 8];
    short8 r;
#pragma unroll
    for (int u = 0; u < 4; ++u) {
      float v0 = w0 * bf2f((ushort)a[2 * u]) + w1 * bf2f((ushort)d[2 * u]) +
                 w2 * bf2f((ushort)e[2 * u]);
      float v1 = w0 * bf2f((ushort)a[2 * u + 1]) + w1 * bf2f((ushort)d[2 * u + 1]) +
                 w2 * bf2f((ushort)e[2 * u + 1]);
      ((unsigned*)&r)[u] = f2bf2(v0, v1);
    }
    *(short8*)(o + D1_ + c * 8) = r;
  }
}

// ---------------------------------------------------------------------------
// MFMA GEMM, 2-phase double-buffered pipeline.
//   A: global_load_lds dbuf (swizzled source, both-sides rule #21).
//   B: BNIN=false -> same DMA path.
//      BNIN=true  -> reg-staged: issue global loads for chunk t+1 early,
//      MFMA chunk t from clean LDS, then transform y=relu(x*sc+sh) and
//      swizzled ds_write — BN work off the ds_read->MFMA critical path.
//   Epilogue: C via padded LDS -> coalesced stores; fused BN partial stats.
// ---------------------------------------------------------------------------
template <int K, bool BNIN>
__global__ __launch_bounds__(256) void gemm_pipe(
    const ushort* __restrict__ Wb, const ushort* __restrict__ Xt,
    const float* __restrict__ bias, const float* __restrict__ scin,
    const float* __restrict__ shin, ushort* __restrict__ Yt,
    float* __restrict__ ps1, float* __restrict__ ps2) {
  constexpr int NT = K / 64;
  __shared__ union SM {
    struct { ushort A[2][128][64]; ushort Bt[2][128][64]; } st;        // 64 KiB
    struct { ushort C[128][132]; float S1[128][33]; float S2[128][33]; } ep;
  } sm;
  __shared__ float scs_l[H_], shs_l[H_];

  int b  = blockIdx.z;
  int n0 = blockIdx.x * 128;
  int m0 = blockIdx.y * 128;
  int tid = threadIdx.x;
  int lane = tid & 63, wid = tid >> 6;
  int wm = (wid >> 1) * 64, wn = (wid & 1) * 64;
  int lr = lane & 15, hi = lane >> 4;
  size_t bn0 = (size_t)b * N_ + n0;

  if (BNIN) {
    for (int i = tid; i < K; i += 256) { scs_l[i] = scin[i]; shs_l[i] = shin[i]; }
  }

  const char* Agb = (const char*)(Wb + (size_t)m0 * K);
  const ushort* Bg = Xt + bn0 * K;
  const char* Bgb = (const char*)Bg;
  const size_t rowB = (size_t)K * 2;

  // per-lane chunk mapping (both-sides swizzle): chunk m -> row=m>>3,
  // physical slot s=m&7, logical 16B-col c=((m&7)-row)&7.
  size_t gsrc[4];
  int    ldst[4];
  int    brow[4], bcol[4];
#pragma unroll
  for (int r = 0; r < 4; ++r) {
    int m = (wid * 4 + r) * 64 + lane;
    int row = m >> 3;
    int c = ((m & 7) - row) & 7;
    gsrc[r] = (size_t)row * rowB + (size_t)c * 16;
    ldst[r] = m * 16;
    brow[r] = row; bcol[r] = c;
  }

  auto stageA = [&](int buf, int kc) {
    char* bA = (char*)sm.st.A[buf];
    size_t kb = (size_t)kc * 128;
#pragma unroll
    for (int r = 0; r < 4; ++r)
      gl_lds16(Agb + gsrc[r] + kb, bA + ldst[r]);
  };
  auto stageB_dma = [&](int buf, int kc) {
    char* bB = (char*)sm.st.Bt[buf];
    size_t kb = (size_t)kc * 128;
#pragma unroll
    for (int r = 0; r < 4; ++r)
      gl_lds16(Bgb + gsrc[r] + kb, bB + ldst[r]);
  };

  short8 braw[4];
  auto loadB = [&](int kc) {
#pragma unroll
    for (int r = 0; r < 4; ++r)
      braw[r] = *(const short8*)&Bg[(size_t)brow[r] * K + kc * 64 + bcol[r] * 8];
  };
  auto writeB = [&](int buf, int kc) {
#pragma unroll
    for (int r = 0; r < 4; ++r) {
      int kb = kc * 64 + bcol[r] * 8;
      short8 pk;
#pragma unroll
      for (int u = 0; u < 4; ++u) {
        float y0 = relu_f(bf2f((ushort)braw[r][2 * u]) * scs_l[kb + 2 * u] +
                          shs_l[kb + 2 * u]);
        float y1 = relu_f(bf2f((ushort)braw[r][2 * u + 1]) * scs_l[kb + 2 * u + 1] +
                          shs_l[kb + 2 * u + 1]);
        ((unsigned*)&pk)[u] = f2bf2(y0, y1);
      }
      *(short8*)((char*)sm.st.Bt[buf] + ldst[r]) = pk;
    }
  };

  f32x4 acc[4][4] = {};

  // prologue
  stageA(0, 0);
  if (BNIN) {
    loadB(0);
    __syncthreads();          // scs ready (+ drains loads)
    writeB(0, 0);
  } else {
    stageB_dma(0, 0);
  }
  __syncthreads();            // chunk 0 fully staged

  int cur = 0;
  for (int t = 0; t < NT; ++t) {
    if (t + 1 < NT) {
      stageA(cur ^ 1, t + 1);
      if (BNIN) loadB(t + 1); else stageB_dma(cur ^ 1, t + 1);
    }
#pragma unroll
    for (int ks = 0; ks < 2; ++ks) {
      short8 af[4], bv[4];
#pragma unroll
      for (int i = 0; i < 4; ++i) {
        int rA = wm + i * 16 + lr;
        int rB = wn + i * 16 + lr;
        int sA = (rA + ks * 4 + hi) & 7;
        int sB = (rB + ks * 4 + hi) & 7;
        af[i] = *(const short8*)&sm.st.A[cur][rA][sA * 8];
        bv[i] = *(const short8*)&sm.st.Bt[cur][rB][sB * 8];
      }
#pragma unroll
      for (int mf = 0; mf < 4; ++mf)
#pragma unroll
        for (int nf = 0; nf < 4; ++nf)
          acc[mf][nf] = __builtin_amdgcn_mfma_f32_16x16x32_bf16(
              af[mf], bv[nf], acc[mf][nf], 0, 0, 0);
    }
    if (BNIN && t + 1 < NT) writeB(cur ^ 1, t + 1);
    __syncthreads();
    cur ^= 1;
  }

  // ---- epilogue: bias, reg stats, C through LDS for coalesced stores ----
  float sum1[4][4] = {}, sum2[4][4] = {};
#pragma unroll
  for (int mf = 0; mf < 4; ++mf) {
#pragma unroll
    for (int nf = 0; nf < 4; ++nf) {
      int n = wn + nf * 16 + lr;
      float v[4];
#pragma unroll
      for (int j = 0; j < 4; ++j) {
        v[j] = acc[mf][nf][j] + bias[m0 + wm + mf * 16 + hi * 4 + j];
        sum1[mf][j] += v[j];
        sum2[mf][j] += v[j] * v[j];
      }
      ushort4 u;
      ((unsigned*)&u)[0] = f2bf2(v[0], v[1]);
      ((unsigned*)&u)[1] = f2bf2(v[2], v[3]);
      *(ushort4*)&sm.ep.C[n][wm + mf * 16 + hi * 4] = u;
    }
  }
  __syncthreads();
  {
    int rown = tid >> 4, q = tid & 15;
#pragma unroll
    for (int p = 0; p < 8; ++p) {
      int n = p * 16 + rown;
      short8 val = *(const short8*)&sm.ep.C[n][q * 8];
      *(short8*)&Yt[(bn0 + n) * H_ + m0 + q * 8] = val;
    }
  }
  int col = (wid & 1) * 16 + lr;
#pragma unroll
  for (int mf = 0; mf < 4; ++mf)
#pragma unroll
    for (int j = 0; j < 4; ++j) {
      int c = wm + mf * 16 + hi * 4 + j;
      sm.ep.S1[c][col] = sum1[mf][j];
      sm.ep.S2[c][col] = sum2[mf][j];
    }
  __syncthreads();
  int pidx = b * gridDim.x + blockIdx.x;
  int c = tid & 127;
  float s = 0.f;
  if (tid < 128) {
#pragma unroll
    for (int k = 0; k < 32; ++k) s += sm.ep.S1[c][k];
    ps1[(size_t)pidx * H_ + m0 + c] = s;
  } else {
#pragma unroll
    for (int k = 0; k < 32; ++k) s += sm.ep.S2[c][k];
    ps2[(size_t)pidx * H_ + m0 + c] = s;
  }
}

// ---------------------------------------------------------------------------
// Reduce P_ partials per channel -> BN scale/shift. One block per channel.
// ---------------------------------------------------------------------------
__global__ __launch_bounds__(256) void bn_stats_fin(
    const float* __restrict__ ps1, const float* __restrict__ ps2,
    const float* __restrict__ gamma, const float* __restrict__ beta,
    float* __restrict__ sc, float* __restrict__ sh) {
  int c = blockIdx.x, t = threadIdx.x;
  float s1 = ps1[(size_t)t * H_ + c] + ps1[(size_t)(t + 256) * H_ + c];
  float s2 = ps2[(size_t)t * H_ + c] + ps2[(size_t)(t + 256) * H_ + c];
  __shared__ float S1[256], S2[256];
  S1[t] = s1; S2[t] = s2;
  __syncthreads();
  for (int off = 128; off > 0; off >>= 1) {
    if (t < off) { S1[t] += S1[t + off]; S2[t] += S2[t + off]; }
    __syncthreads();
  }
  if (t == 0) {
    const float inv = 1.0f / (float)(B_ * N_);
    float mean = S1[0] * inv;
    float var  = S2[0] * inv - mean * mean;
    float g    = gamma[c] * rsqrtf(var + 1e-5f);
    sc[c] = g;
    sh[c] = beta[c] - mean * g;
  }
}

// ---------------------------------------------------------------------------
// Final: h2b[b][n][m] bf16 (pre-BN) -> BN+ReLU -> d_out[b][m][n] fp32.
// 3-D grid: (N/32, H/128, B).
// ---------------------------------------------------------------------------
__global__ __launch_bounds__(256) void bn_out_t(
    const ushort* __restrict__ Hb, const float* __restrict__ sc,
    const float* __restrict__ sh, float* __restrict__ out) {
  __shared__ float tile[32][132];   // [n][m]
  int b = blockIdx.z;
  int n0 = blockIdx.x * 32, m0 = blockIdx.y * 128;
  int t = threadIdx.x;
  int m8 = (t & 15) * 8;
  f32x4 sa = *(const f32x4*)&sc[m0 + m8];
  f32x4 sb = *(const f32x4*)&sc[m0 + m8 + 4];
  f32x4 ha = *(const f32x4*)&sh[m0 + m8];
  f32x4 hb = *(const f32x4*)&sh[m0 + m8 + 4];
  size_t bn0 = (size_t)b * N_ + n0;
#pragma unroll
  for (int pass = 0; pass < 2; ++pass) {
    int n = pass * 16 + (t >> 4);
    short8 v = *(const short8*)&Hb[(bn0 + n) * H_ + m0 + m8];
#pragma unroll
    for (int e = 0; e < 4; ++e) {
      tile[n][m8 + e]     = relu_f(bf2f((ushort)v[e]) * sa[e] + ha[e]);
      tile[n][m8 + 4 + e] = relu_f(bf2f((ushort)v[e + 4]) * sb[e] + hb[e]);
    }
  }
  __syncthreads();
  int m = t >> 1, nh = (t & 1) * 16;
  float* orow = out + ((size_t)b * H_ + m0 + m) * N_ + n0 + nh;
#pragma unroll
  for (int j = 0; j < 4; ++j) {
    float4 v;
    v.x = tile[nh + j * 4 + 0][m];
    v.y = tile[nh + j * 4 + 1][m];
    v.z = tile[nh + j * 4 + 2][m];
    v.w = tile[nh + j * 4 + 3][m];
    *(float4*)&orow[j * 4] = v;
  }
}

// ---------------------------------------------------------------------------
extern "C" void kernel_launch(void* const* d_in, const int* in_sizes, int n_in,
                              void* d_out, int out_size, void* d_ws,
                              size_t ws_size, hipStream_t stream) {
  const float* xyz1    = (const float*)d_in[0];
  const float* xyz2    = (const float*)d_in[1];
  const float* points1 = (const float*)d_in[2];
  const float* points2 = (const float*)d_in[3];
  const float* W1  = (const float*)d_in[4];
  const float* b1  = (const float*)d_in[5];
  const float* g1  = (const float*)d_in[6];
  const float* bt1 = (const float*)d_in[7];
  const float* W2  = (const float*)d_in[8];
  const float* b2  = (const float*)d_in[9];
  const float* g2  = (const float*)d_in[10];
  const float* bt2 = (const float*)d_in[11];
  float* out = (float*)d_out;
  char* cur = (char*)d_ws;
  auto alloc = [&](size_t bytes) { char* p = cur; cur += (bytes + 255) & ~255ull; return p; };

  ushort* p2tb = (ushort*)alloc((size_t)B_ * S_ * D2_ * 2);   // [B][S][256]
  float*  pd   = (float*)alloc((size_t)B_ * N_ * CH_ * 3 * 4);
  int*    pi   = (int*)alloc((size_t)B_ * N_ * CH_ * 3 * 4);
  ushort* W1b  = (ushort*)alloc((size_t)H_ * CIN_ * 2);
  ushort* W2b  = (ushort*)alloc((size_t)H_ * H_ * 2);
  ushort* xct  = (ushort*)alloc((size_t)B_ * N_ * CIN_ * 2);  // [B][N][320]
  ushort* h1t  = (ushort*)alloc((size_t)B_ * N_ * H_ * 2);    // [B][N][256]
  float*  ps1  = (float*)alloc((size_t)P_ * H_ * 4);
  float*  ps2  = (float*)alloc((size_t)P_ * H_ * 4);
  float*  sc1  = (float*)alloc(H_ * 4);
  float*  sh1  = (float*)alloc(H_ * 4);
  float*  sc2  = (float*)alloc(H_ * 4);
  float*  sh2  = (float*)alloc(H_ * 4);
  ushort* h2b  = xct;   // overlay: xct dead after gemm1

  // 1) points2 transpose + weight conversions + chunked 3-NN (merged)
  prep_knn<<<4096 + 40 + 32 + 2048, 256, 0, stream>>>(
      points2, W1, W2, xyz1, xyz2, p2tb, W1b, W2b, pd, pi);

  // 2) merge + points1-transpose + interp -> xct [B][N][320] bf16
  build_fused<<<B_ * N_ / 16, 256, 0, stream>>>(points1, p2tb, pd, pi, xct);

  // 3) layer-1 GEMM + fused stats
  gemm_pipe<CIN_, false><<<dim3(N_ / 128, H_ / 128, B_), 256, 0, stream>>>(
      W1b, xct, b1, nullptr, nullptr, h1t, ps1, ps2);
  // 4) BN1 fold
  bn_stats_fin<<<H_, 256, 0, stream>>>(ps1, ps2, g1, bt1, sc1, sh1);

  // 5) layer-2 GEMM (BN1+ReLU at B-staging, off the MFMA path) + stats
  gemm_pipe<H_, true><<<dim3(N_ / 128, H_ / 128, B_), 256, 0, stream>>>(
      W2b, h1t, b2, sc1, sh1, h2b, ps1, ps2);
  // 6) BN2 fold
  bn_stats_fin<<<H_, 256, 0, stream>>>(ps1, ps2, g2, bt2, sc2, sh2);

  // 7) final BN+ReLU + transpose to d_out [b][m][n] fp32
  bn_out_t<<<dim3(N_ / 32, H_ / 128, B_), 256, 0, stream>>>(h2b, sc2, sh2, out);
}